// Round 5
// baseline (451.008 us; speedup 1.0000x reference)
//
#include <hip/hip_runtime.h>
#include <math.h>

#define N_ROWS 4096
#define E_DIM  512
#define C_CLS  50257
#define NCH    786            // ceil(50257/64) col chunks of 64
#define NGRP   16             // col groups (blockIdx.y); pl = [N_ROWS][NGRP]
#define COS_M  (-0.6536436208636119f)   // cos(4.0)
#define SIN_M  (-0.7568024953079282f)   // sin(4.0)
#define EPSN   1e-12f

typedef __bf16 bf16x8 __attribute__((ext_vector_type(8)));
typedef float  f32x4  __attribute__((ext_vector_type(4)));
typedef unsigned short ushort8 __attribute__((ext_vector_type(8)));

__device__ inline unsigned short f2bf(float f) {
  unsigned int u = __float_as_uint(f);
  u += 0x7FFFu + ((u >> 16) & 1u);     // round-to-nearest-even
  return (unsigned short)(u >> 16);
}
__device__ inline float bf2f(unsigned short u) {
  return __uint_as_float((unsigned)u << 16);
}

// Fused normalize kernel (one launch instead of two):
//  blocks [0, N_ROWS)            : x-row L2-normalize + fp32 target cos tv +
//                                  bf16-rounded target cos tb (label logic
//                                  lives here, NOT in the GEMM hot loop).
//  blocks [N_ROWS, N_ROWS+12565) : w-row L2-normalize (4 rows/block,
//                                  wave-private, no barriers).
__global__ __launch_bounds__(256) void k_norm(const float* __restrict__ x,
                                              const float* __restrict__ w,
                                              const int* __restrict__ label,
                                              unsigned short* __restrict__ nx,
                                              unsigned short* __restrict__ nw,
                                              float* __restrict__ tv,
                                              float* __restrict__ tb) {
  if (blockIdx.x >= N_ROWS) {
    // ---- w-normalize part ----
    int row = (blockIdx.x - N_ROWS) * 4 + (threadIdx.x >> 6);
    if (row >= C_CLS) return;
    int lane = threadIdx.x & 63;
    const float4* p = (const float4*)(w + (size_t)row * E_DIM);
    float4 v0 = p[lane * 2], v1 = p[lane * 2 + 1];
    float ss = v0.x*v0.x + v0.y*v0.y + v0.z*v0.z + v0.w*v0.w
             + v1.x*v1.x + v1.y*v1.y + v1.z*v1.z + v1.w*v1.w;
    #pragma unroll
    for (int m = 32; m > 0; m >>= 1) ss += __shfl_xor(ss, m, 64);
    float inv = 1.0f / fmaxf(sqrtf(ss), EPSN);
    ushort8 o;
    o[0]=f2bf(v0.x*inv); o[1]=f2bf(v0.y*inv); o[2]=f2bf(v0.z*inv); o[3]=f2bf(v0.w*inv);
    o[4]=f2bf(v1.x*inv); o[5]=f2bf(v1.y*inv); o[6]=f2bf(v1.z*inv); o[7]=f2bf(v1.w*inv);
    *(ushort8*)(nw + (size_t)row * E_DIM + lane * 8) = o;
    return;
  }
  // ---- x-normalize part ----
  int row = blockIdx.x;
  int lab = label[row];
  int tid = threadIdx.x;
  const float2* px = (const float2*)(x + (size_t)row * E_DIM);
  const float2* pw = (const float2*)(w + (size_t)lab * E_DIM);
  float2 a = px[tid], b = pw[tid];
  float sx = a.x*a.x + a.y*a.y;
  float sw = b.x*b.x + b.y*b.y;
  float sd = a.x*b.x + a.y*b.y;
  #pragma unroll
  for (int off = 32; off > 0; off >>= 1) {
    sx += __shfl_down(sx, off, 64);
    sw += __shfl_down(sw, off, 64);
    sd += __shfl_down(sd, off, 64);
  }
  __shared__ float sb[3][4];
  __shared__ float sb2[4];
  if ((tid & 63) == 0) {
    sb[0][tid >> 6] = sx; sb[1][tid >> 6] = sw; sb[2][tid >> 6] = sd;
  }
  __syncthreads();
  float SX = sb[0][0] + sb[0][1] + sb[0][2] + sb[0][3];
  float SW = sb[1][0] + sb[1][1] + sb[1][2] + sb[1][3];
  float invx = 1.0f / fmaxf(sqrtf(SX), EPSN);
  float invw = 1.0f / fmaxf(sqrtf(SW), EPSN);
  ushort2 o;
  o.x = f2bf(a.x * invx);
  o.y = f2bf(a.y * invx);
  ((ushort2*)(nx + (size_t)row * E_DIM))[tid] = o;
  // bf16-rounded dot: same element rounding the GEMM sees (nx and nw paths).
  float s2 = bf2f(o.x) * bf2f(f2bf(b.x * invw))
           + bf2f(o.y) * bf2f(f2bf(b.y * invw));
  #pragma unroll
  for (int off = 32; off > 0; off >>= 1) s2 += __shfl_down(s2, off, 64);
  if ((tid & 63) == 0) sb2[tid >> 6] = s2;
  __syncthreads();
  if (tid == 0) {
    float SD = sb[2][0] + sb[2][1] + sb[2][2] + sb[2][3];
    tv[row] = SD / (fmaxf(sqrtf(SX), EPSN) * fmaxf(sqrtf(SW), EPSN));
    tb[row] = sb2[0] + sb2[1] + sb2[2] + sb2[3];
  }
}

// ---------------------------------------------------------------------------
// Persistent column-streaming GEMM, DUAL-PORT B feed.
//
// Round-4 counters: 8.8K cyc/chunk ~= the LDS-port floor (512 KB stage-write
// + 512 KB read = 1 MB/chunk @ ~112-128 B/cyc), with the MFMA floor at 5.0K.
// Per-wave B LDS-read traffic is fixed at the B-tile size regardless of
// blocking, so the fix is to split B across the CU's TWO independent data
// ports: cols 0-47 of each 64-col chunk stream through LDS (staged once,
// read by all 8 waves); cols 48-63 are DIRECT per-wave global loads served
// by L2/L3 (nw = 51.5 MB is fully L3-resident; the 8x per-CU re-read is
// cache-absorbed). New floors: LDS 432 KB ~= 3.9K cyc, vector-path 176 KB
// ~= 2.9K cyc, MFMA 5.0K cyc -> MFMA-bound.
//
// Direct-path frags are depth-1 prefetched (L2-hit ~200 cyc < ~310 cyc of
// MFMA per ks-slot per SIMD). A-slab (32 rows x K=512 = 128 VGPR) stays
// pinned via volatile inline-asm loads (round-3/4 lesson). One barrier per
// chunk; thin interior epilogue (32 exp + add), masked tail only at c=NCH-1.
// ---------------------------------------------------------------------------
#define GLDS(gp, lp) __builtin_amdgcn_global_load_lds( \
    (const __attribute__((address_space(1))) void*)(gp), \
    (__attribute__((address_space(3))) void*)(lp), 16, 0, 0)

__global__ __launch_bounds__(512, 2) void k_gemm(const unsigned short* __restrict__ nx,
                                                 const unsigned short* __restrict__ nw,
                                                 float* __restrict__ pl) {
  __shared__ unsigned char ldsB[2][49152];   // 2 x (48 cols x 512 k x 2 B)

  const int rtile = blockIdx.x;              // 0..15
  const int grp   = blockIdx.y;              // 0..15
  const int c0    = grp * 49 + (grp < 2 ? grp : 2);   // chunk range [c0, c1)
  const int c1    = c0 + 49 + (grp < 2 ? 1 : 0);      // groups 0,1 take 50

  const int tid  = threadIdx.x;
  const int wave = tid >> 6;
  const int lane = tid & 63;
  const int q    = lane >> 4;
  const int l15  = lane & 15;
  const int row0 = rtile * 256 + wave * 32;  // wave's first output row

  // LDS portion: cols [c*64, c*64+48). 48 fragment chunks of 1 KB,
  // ch = cf*16+ks covers cols [cf*16,+16) x k [ks*32,+32); lane (q,l15)
  // supplies col cf*16+l15, k ks*32+q*8..+7 -> lands at base+lane*16.
  auto stageB = [&](int c, int p) {
    unsigned cb = (unsigned)c * 64u;
    #pragma unroll
    for (int i = 0; i < 6; i++) {
      int ch = wave * 6 + i;                 // wave-uniform
      unsigned col = cb + (unsigned)((ch >> 4) * 16 + l15);
      if (col >= C_CLS) col = C_CLS - 1;     // clamp; masked in tail epilogue
      unsigned off = col * (unsigned)E_DIM + (unsigned)((ch & 15) * 32 + q * 8);
      GLDS(nw + off, &ldsB[p][ch * 1024]);
    }
  };
  // Direct portion: cols [c*64+48, c*64+64), one frag per ks, per wave.
  auto dirbase = [&](int c) -> const unsigned short* {
    unsigned col = (unsigned)c * 64u + 48u + (unsigned)l15;
    if (col >= C_CLS) col = C_CLS - 1;       // tail clamp; masked in epilogue
    return nw + (size_t)col * E_DIM + q * 8;
  };

  // Issue first LDS stage, then load A-slab while it flies.
  stageB(c0, c0 & 1);

  // A-slab: 32 rows x K=512 in registers for the whole block, loaded with
  // volatile inline asm so the compiler can neither sink nor rematerialize.
  f32x4 araw[2][16];
  #pragma unroll
  for (int rf = 0; rf < 2; rf++)
    #pragma unroll
    for (int kf = 0; kf < 16; kf++) {
      const unsigned short* pa = nx + (size_t)(row0 + rf * 16 + l15) * E_DIM
                                    + kf * 32 + q * 8;
      asm volatile("global_load_dwordx4 %0, %1, off"
                   : "=v"(araw[rf][kf]) : "v"(pa));
    }
  asm volatile("s_waitcnt vmcnt(0)" ::: "memory");
  bf16x8 a[2][16];
  #pragma unroll
  for (int rf = 0; rf < 2; rf++)
    #pragma unroll
    for (int kf = 0; kf < 16; kf++)
      a[rf][kf] = __builtin_bit_cast(bf16x8, araw[rf][kf]);

  float e[8] = {};                           // per-lane partial exp-sums

  // Prime the direct-path pipeline: (c0, ks=0).
  const unsigned short* b3 = dirbase(c0);
  bf16x8 dA = *(const bf16x8*)(b3);

  __syncthreads();                           // chunk c0 landed everywhere

  for (int c = c0; c < c1; ++c) {
    const int p = c & 1;
    if (c + 1 < c1) stageB(c + 1, p ^ 1);    // depth-1 LDS prefetch
    const unsigned short* b3n = (c + 1 < c1) ? dirbase(c + 1) : b3;

    f32x4 acc[2][4] = {};
    const unsigned char* bb = &ldsB[p][0];
    #pragma unroll
    for (int ks = 0; ks < 16; ks++) {
      // Depth-1 direct prefetch: next ks (or next chunk's ks=0 at ks=15).
      bf16x8 dN;
      if (ks < 15) dN = *(const bf16x8*)(b3 + (ks + 1) * 32);
      else         dN = *(const bf16x8*)(b3n);
      bf16x8 bfr[3];
      #pragma unroll
      for (int cf = 0; cf < 3; cf++)
        bfr[cf] = *(const bf16x8*)(bb + (unsigned)((cf * 16 + ks) * 1024)
                                      + (unsigned)lane * 16u);
      #pragma unroll
      for (int rf = 0; rf < 2; rf++) {
        #pragma unroll
        for (int cf = 0; cf < 3; cf++)
          acc[rf][cf] = __builtin_amdgcn_mfma_f32_16x16x32_bf16(
              a[rf][ks], bfr[cf], acc[rf][cf], 0, 0, 0);
        acc[rf][3] = __builtin_amdgcn_mfma_f32_16x16x32_bf16(
            a[rf][ks], dA, acc[rf][3], 0, 0, 0);
      }
      dA = dN;
    }
    b3 = b3n;

    // Thin per-chunk epilogue: exp + accumulate; compares only in the tail.
    if (c != NCH - 1) {
      #pragma unroll
      for (int rf = 0; rf < 2; rf++)
        #pragma unroll
        for (int r = 0; r < 4; r++)
          #pragma unroll
          for (int cf = 0; cf < 4; cf++)
            e[rf * 4 + r] += __expf(acc[rf][cf][r]);
    } else {
      const int ccol = c * 64;
      #pragma unroll
      for (int rf = 0; rf < 2; rf++)
        #pragma unroll
        for (int r = 0; r < 4; r++)
          #pragma unroll
          for (int cf = 0; cf < 4; cf++) {
            int col = ccol + cf * 16 + l15;
            if (col < C_CLS) e[rf * 4 + r] += __expf(acc[rf][cf][r]);
          }
    }

    __syncthreads();   // vmcnt(0): stage c+1 landed (covered by chunk work);
                       // lgkmcnt(0): my buf-p reads retired; barrier: all waves
                       // done with buf p -> next iter may stage c+2 into it.
  }

  // Once-per-block reduce of e over the 16-lane col group + pl store.
  #pragma unroll
  for (int i = 0; i < 8; i++) {
    float s = e[i];
    #pragma unroll
    for (int m = 1; m < 16; m <<= 1) s += __shfl_xor(s, m, 64);
    if (l15 == 0) {
      int grow = row0 + (i >> 2) * 16 + 4 * q + (i & 3);
      pl[(size_t)grow * NGRP + grp] = s;
    }
  }
}

// One thread per row: sum 16 group partials, swap in margin logit, mean-reduce.
__global__ __launch_bounds__(256) void k_reduce(const float* __restrict__ pl,
                                               const float* __restrict__ tv,
                                               const float* __restrict__ tb,
                                               float* __restrict__ out) {
  int row = blockIdx.x * 256 + threadIdx.x;
  const float4* p = (const float4*)(pl + (size_t)row * NGRP);
  float4 s0 = p[0], s1 = p[1], s2 = p[2], s3 = p[3];
  float S = (s0.x + s0.y + s0.z + s0.w) + (s1.x + s1.y + s1.z + s1.w)
          + (s2.x + s2.y + s2.z + s2.w) + (s3.x + s3.y + s3.z + s3.w);
  float t = tv[row];
  float tbl = tb[row];
  float sint = sqrtf(fmaxf(0.f, 1.f - t * t));
  float cosm = t * COS_M - sint * SIN_M;
  float Sp = S - __expf(tbl) + __expf(cosm);  // replace target logit
  float loss = logf(Sp) - cosm;
  #pragma unroll
  for (int m = 32; m > 0; m >>= 1) loss += __shfl_xor(loss, m, 64);
  if ((threadIdx.x & 63) == 0) atomicAdd(out, loss * (1.0f / N_ROWS));
}

extern "C" void kernel_launch(void* const* d_in, const int* in_sizes, int n_in,
                              void* d_out, int out_size, void* d_ws, size_t ws_size,
                              hipStream_t stream) {
  const float* x = (const float*)d_in[0];
  const int* label = (const int*)d_in[1];
  const float* w = (const float*)d_in[2];
  float* out = (float*)d_out;
  char* ws = (char*)d_ws;

  size_t off = 0;
  unsigned short* nx = (unsigned short*)(ws + off); off += (size_t)N_ROWS * E_DIM * 2;  // 4 MB
  unsigned short* nw = (unsigned short*)(ws + off); off += (size_t)C_CLS * E_DIM * 2;   // 51.5 MB
  float* tv  = (float*)(ws + off); off += (size_t)N_ROWS * 4;
  float* tb  = (float*)(ws + off); off += (size_t)N_ROWS * 4;
  float* pl  = (float*)(ws + off); off += (size_t)N_ROWS * NGRP * 4;                    // 256 KB

  hipMemsetAsync(d_out, 0, sizeof(float), stream);
  int nwBlocks = (C_CLS + 3) / 4;
  k_norm<<<N_ROWS + nwBlocks, 256, 0, stream>>>(x, w, label, nx, nw, tv, tb);
  dim3 g(16, 16);
  k_gemm<<<g, 512, 0, stream>>>(nx, nw, pl);
  k_reduce<<<N_ROWS / 256, 256, 0, stream>>>(pl, tv, tb, out);
}